// Round 1
// baseline (40.995 us; speedup 1.0000x reference)
//
#include <hip/hip_runtime.h>
#include <hip/hip_bf16.h>
#include <math.h>

#define TOPK 8

// Kernel 1: one block per (b,k) row. Sum of squared diffs over D, times weight.
__global__ __launch_bounds__(256) void row_loss_kernel(
    const float* __restrict__ out,
    const float* __restrict__ tgt,
    const float* __restrict__ w,
    float* __restrict__ loss,
    int d_over_1024)  // D / (256*4)
{
    const int row = blockIdx.x;
    const size_t base = (size_t)row * (size_t)(d_over_1024 * 1024);
    const float4* __restrict__ o4 = (const float4*)(out + base);
    const float4* __restrict__ t4 = (const float4*)(tgt + base);
    const int tid = threadIdx.x;

    float acc = 0.0f;
    // D=3072 -> d_over_1024 = 3 iterations of float4 per thread
    for (int i = 0; i < d_over_1024; ++i) {
        float4 a = o4[tid + i * 256];
        float4 b = t4[tid + i * 256];
        float dx = a.x - b.x;
        float dy = a.y - b.y;
        float dz = a.z - b.z;
        float dw = a.w - b.w;
        acc += dx * dx + dy * dy + dz * dz + dw * dw;
    }

    // wave-64 reduction
    #pragma unroll
    for (int off = 32; off > 0; off >>= 1)
        acc += __shfl_down(acc, off, 64);

    __shared__ float s[4];
    const int lane = tid & 63;
    const int wid = tid >> 6;
    if (lane == 0) s[wid] = acc;
    __syncthreads();
    if (tid == 0) {
        float tot = s[0] + s[1] + s[2] + s[3];
        loss[row] = tot * w[row];
    }
}

// Kernel 2: single block, one thread per batch element b.
// Each thread: top-8 of its 17 losses, mean; then block-mean over B.
__global__ __launch_bounds__(512) void topk_mean_kernel(
    const float* __restrict__ loss,
    float* __restrict__ outp,
    int B, int K)
{
    const int b = threadIdx.x;
    float per = 0.0f;

    if (b < B) {
        // K = 17 fixed at compile time for register residency
        float v[17];
        #pragma unroll
        for (int k = 0; k < 17; ++k)
            v[k] = loss[b * 17 + k];

        float sum8 = 0.0f;
        #pragma unroll
        for (int it = 0; it < TOPK; ++it) {
            float m = v[0];
            int mi = 0;
            #pragma unroll
            for (int k = 1; k < 17; ++k) {
                if (v[k] > m) { m = v[k]; mi = k; }
            }
            sum8 += m;
            // static-indexed clear (avoid runtime-indexed array -> scratch)
            #pragma unroll
            for (int k = 0; k < 17; ++k)
                v[k] = (k == mi) ? -INFINITY : v[k];
        }
        per = sum8 * (1.0f / (float)TOPK);
    }

    // block reduction over 512 threads (8 waves)
    #pragma unroll
    for (int off = 32; off > 0; off >>= 1)
        per += __shfl_down(per, off, 64);

    __shared__ float s[8];
    const int lane = threadIdx.x & 63;
    const int wid = threadIdx.x >> 6;
    if (lane == 0) s[wid] = per;
    __syncthreads();
    if (threadIdx.x == 0) {
        float tot = 0.0f;
        #pragma unroll
        for (int i = 0; i < 8; ++i) tot += s[i];
        outp[0] = tot / (float)B;
    }
}

extern "C" void kernel_launch(void* const* d_in, const int* in_sizes, int n_in,
                              void* d_out, int out_size, void* d_ws, size_t ws_size,
                              hipStream_t stream) {
    const float* out_p = (const float*)d_in[0];
    const float* tgt_p = (const float*)d_in[1];
    const float* w_p   = (const float*)d_in[2];
    float* res = (float*)d_out;

    const int BK = in_sizes[2];            // 512*17 = 8704
    const int D  = in_sizes[0] / BK;       // 3072
    const int K  = 17;
    const int B  = BK / K;                 // 512

    float* loss_ws = (float*)d_ws;         // BK floats

    row_loss_kernel<<<BK, 256, 0, stream>>>(out_p, tgt_p, w_p, loss_ws, D / 1024);
    topk_mean_kernel<<<1, 512, 0, stream>>>(loss_ws, res, B, K);
}